// Round 7
// baseline (76.882 us; speedup 1.0000x reference)
//
#include <hip/hip_runtime.h>
#include <math.h>

#define TEMP   13.544f
#define PLAT   18.420680743952367      // -ln(1e-8)
#define KH     384                     // harmonics k = 0..383
#define DIMF   (2*KH)                  // 768 dims: [0..383]=cos_k, [384..767]=sin_k
#define MDCT   2048
#define TSG    64                      // gemm tile
#define BKG    16
#define SPLITK 8

// ---------- setup: per-batch mask decode + nv + zero sums + batch absmax ----------
__global__ __launch_bounds__(256) void setup_kernel(const float* __restrict__ X,
                                                    const void* __restrict__ mask_raw,
                                                    int B, int N,
                                                    int* __restrict__ msk,
                                                    int* __restrict__ nv,
                                                    double* __restrict__ sums,
                                                    float* __restrict__ mxb) {
    int b = blockIdx.x, t = threadIdx.x;
    __shared__ int flags[2];
    __shared__ int cnt[4];
    __shared__ float fmx[4];
    if (t < 2) flags[t] = 0;
    __syncthreads();
    const unsigned int* mi = (const unsigned int*)mask_raw;
    int total = B * N;
    int scan = total < 256 ? total : 256;
    if (t < scan) {
        unsigned int v = mi[t];
        if (v == 0x3F800000u) atomicOr(&flags[0], 1);
        else if (v > 1u)      atomicOr(&flags[1], 1);
    }
    __syncthreads();
    int layout = flags[0] ? 2 : (flags[1] ? 1 : 0);  // 0=i32, 1=u8, 2=f32

    int c = 0;
    for (int j = t; j < N; j += 256) {
        int v;
        if (layout == 0)      v = (((const int*)mask_raw)[b * N + j] != 0);
        else if (layout == 1) v = (((const unsigned char*)mask_raw)[b * N + j] != 0);
        else                  v = (((const float*)mask_raw)[b * N + j] != 0.0f);
        msk[b * N + j] = v;
        c += v;
    }
    // batch absmax of X
    const float4* X4 = (const float4*)(X + (size_t)b * N * 16);
    int n4 = N * 4;
    float m = 0.0f;
    for (int i = t; i < n4; i += 256) {
        float4 v = X4[i];
        m = fmaxf(m, fmaxf(fmaxf(fabsf(v.x), fabsf(v.y)), fmaxf(fabsf(v.z), fabsf(v.w))));
    }
    #pragma unroll
    for (int off = 32; off > 0; off >>= 1) {
        c += __shfl_down(c, off, 64);
        m  = fmaxf(m, __shfl_down(m, off, 64));
    }
    int lane = t & 63, wid = t >> 6;
    if (lane == 0) { cnt[wid] = c; fmx[wid] = m; }
    __syncthreads();
    if (t == 0) {
        nv[b] = cnt[0] + cnt[1] + cnt[2] + cnt[3];
        mxb[b] = fmaxf(fmaxf(fmx[0], fmx[1]), fmaxf(fmx[2], fmx[3]));
        sums[b * 2 + 0] = 0.0;
        sums[b * 2 + 1] = 0.0;
    }
}

__device__ __forceinline__ double compute_L(const float* mxb, int B, double a, double bb) {
    double mx = 0.0;
    for (int b = 0; b < B; b++) mx = fmax(mx, (double)mxb[b]);
    double dsat = sqrt(fmax(35.0 + bb, 0.0) / a);
    return fmax(2.0 * mx + 1.0, dsat + 1.5);
}

// ---------- dct: block k computes Fourier coefficient c_k of g = f - PLAT ----------
__global__ __launch_bounds__(256) void dct_kernel(const float* __restrict__ pa,
                                                  const float* __restrict__ pb,
                                                  const float* __restrict__ mxb,
                                                  int B,
                                                  float* __restrict__ cdim) {
    int k = blockIdx.x, t = threadIdx.x;
    double a = (double)pa[0]; if (a < 1e-30) a = 1e-30;
    double bb = (double)pb[0];
    double L = compute_L(mxb, B, a, bb);
    double om = (double)k * M_PI / L;
    double h = L / (double)MDCT;
    double acc = 0.0;
    for (int m = t; m < MDCT; m += 256) {
        double d = ((double)m + 0.5) * h;
        double z = a * (d * d) - bb;
        double sig = 1.0 / (1.0 + exp(z));
        double g = -log(sig + 1e-8) - PLAT;
        acc += g * cos(om * d);
    }
    #pragma unroll
    for (int off = 32; off > 0; off >>= 1) acc += __shfl_down(acc, off, 64);
    __shared__ double ws[4];
    int lane = t & 63, wid = t >> 6;
    if (lane == 0) ws[wid] = acc;
    __syncthreads();
    if (t == 0) {
        double c = (ws[0] + ws[1] + ws[2] + ws[3]) * ((k == 0 ? 1.0 : 2.0) / (double)MDCT);
        cdim[k]      = (float)c;   // cos dim
        cdim[KH + k] = (float)c;   // sin dim (sin_0 features are 0, harmless)
    }
}

// ---------- features: block (row,b), thread k: C_k and S_k sums over 16 elems ----------
__global__ __launch_bounds__(384) void feat_kernel(const float* __restrict__ X,
                                                   const float* __restrict__ pa,
                                                   const float* __restrict__ pb,
                                                   const float* __restrict__ mxb,
                                                   int B, int N,
                                                   float* __restrict__ Phi) {
    int row = blockIdx.x, b = blockIdx.y, t = threadIdx.x;
    __shared__ float xs[16];
    if (t < 16) xs[t] = X[((size_t)b * N + row) * 16 + t];
    __syncthreads();
    double a = (double)pa[0]; if (a < 1e-30) a = 1e-30;
    double bb = (double)pb[0];
    double L = compute_L(mxb, B, a, bb);
    double om = (double)t * M_PI / L;
    const double inv2pi = 0.15915494309189535;
    const double twopi  = 6.283185307179586;
    float cs = 0.0f, sn = 0.0f;
    #pragma unroll
    for (int e = 0; e < 16; e++) {
        double th = om * (double)xs[e];
        double n = rint(th * inv2pi);
        float tr = (float)(th - twopi * n);
        float s, c;
        __sincosf(tr, &s, &c);
        cs += c; sn += s;
    }
    size_t base = (size_t)b * DIMF * N;
    Phi[base + (size_t)t * N + row]        = cs;
    Phi[base + (size_t)(KH + t) * N + row] = sn;
}

// ---------- gemm: tsm_part = (c.*Phi_i) . Phi_j over k-chunk; 64x64 tile, 4x4/thread ----------
__global__ __launch_bounds__(256) void gemm_kernel(const float* __restrict__ Phi,
                                                   const float* __restrict__ cdim,
                                                   const int* __restrict__ nv,
                                                   float* __restrict__ parts,
                                                   int B, int N) {
    const int b = blockIdx.z, sk = blockIdx.y, tile = blockIdx.x;
    const int nt = N / TSG;
    const int ti0 = (tile / nt) * TSG, tj0 = (tile % nt) * TSG;
    const int nvb = nv[b];
    if (ti0 >= nvb || tj0 >= nvb) return;   // contiguous-prefix mask: dead tile

    __shared__ float As[BKG][TSG];
    __shared__ float Bs[BKG][TSG];
    const int t = threadIdx.x, tr = t >> 4, tc = t & 15;
    float acc[4][4] = {{0.0f}};
    const float* Pb = Phi + (size_t)b * DIMF * N;
    const int chunk = DIMF / SPLITK;        // 96
    const int kbase = sk * chunk;

    const int skk = t >> 4;                 // staging k-row (0..15)
    const int sr4 = (t & 15) * 4;           // staging col*4

    for (int ch = 0; ch < chunk; ch += BKG) {
        int kb = kbase + ch;
        __syncthreads();
        {
            float ck = cdim[kb + skk];
            const float4 av = *(const float4*)&Pb[(size_t)(kb + skk) * N + ti0 + sr4];
            const float4 bv = *(const float4*)&Pb[(size_t)(kb + skk) * N + tj0 + sr4];
            *(float4*)&As[skk][sr4] = make_float4(av.x * ck, av.y * ck, av.z * ck, av.w * ck);
            *(float4*)&Bs[skk][sr4] = bv;
        }
        __syncthreads();
        #pragma unroll
        for (int kk = 0; kk < BKG; kk++) {
            float4 a4 = *(const float4*)&As[kk][tr * 4];
            float4 b4 = *(const float4*)&Bs[kk][tc * 4];
            acc[0][0] = fmaf(a4.x, b4.x, acc[0][0]);
            acc[0][1] = fmaf(a4.x, b4.y, acc[0][1]);
            acc[0][2] = fmaf(a4.x, b4.z, acc[0][2]);
            acc[0][3] = fmaf(a4.x, b4.w, acc[0][3]);
            acc[1][0] = fmaf(a4.y, b4.x, acc[1][0]);
            acc[1][1] = fmaf(a4.y, b4.y, acc[1][1]);
            acc[1][2] = fmaf(a4.y, b4.z, acc[1][2]);
            acc[1][3] = fmaf(a4.y, b4.w, acc[1][3]);
            acc[2][0] = fmaf(a4.z, b4.x, acc[2][0]);
            acc[2][1] = fmaf(a4.z, b4.y, acc[2][1]);
            acc[2][2] = fmaf(a4.z, b4.z, acc[2][2]);
            acc[2][3] = fmaf(a4.z, b4.w, acc[2][3]);
            acc[3][0] = fmaf(a4.w, b4.x, acc[3][0]);
            acc[3][1] = fmaf(a4.w, b4.y, acc[3][1]);
            acc[3][2] = fmaf(a4.w, b4.z, acc[3][2]);
            acc[3][3] = fmaf(a4.w, b4.w, acc[3][3]);
        }
    }
    float* dst = parts + (((size_t)sk * B + b) * N) * N;
    #pragma unroll
    for (int i2 = 0; i2 < 4; i2++) {
        *(float4*)&dst[(size_t)(ti0 + tr * 4 + i2) * N + tj0 + tc * 4] =
            make_float4(acc[i2][0], acc[i2][1], acc[i2][2], acc[i2][3]);
    }
}

// ---------- reduce splitK parts -> tsm, fused masked f64 stats ----------
__global__ __launch_bounds__(256) void reduce_stats_kernel(const float* __restrict__ parts,
                                                           const int* __restrict__ msk,
                                                           float* __restrict__ tsm,
                                                           double* __restrict__ sums,
                                                           int B, int N) {
    const int i = blockIdx.x, b = blockIdx.y, t = threadIdx.x;
    float* orow = tsm + ((size_t)b * N + i) * N;
    const int mi = msk[b * N + i];
    double s = 0.0, s2 = 0.0;
    for (int c = 0; c < N / 256; c++) {
        int j = t + c * 256;
        float v = 0.0f;
        #pragma unroll
        for (int sk = 0; sk < SPLITK; sk++)
            v += parts[(((size_t)sk * B + b) * N + i) * N + j];
        float val = (float)PLAT + v * (1.0f / 256.0f);
        orow[j] = val;
        if (mi && msk[b * N + j]) { double x = (double)val; s += x; s2 += x * x; }
    }
    #pragma unroll
    for (int off = 32; off > 0; off >>= 1) {
        s  += __shfl_down(s,  off, 64);
        s2 += __shfl_down(s2, off, 64);
    }
    __shared__ double ws[4], ws2[4];
    int lane = t & 63, wid = t >> 6;
    if (lane == 0) { ws[wid] = s; ws2[wid] = s2; }
    __syncthreads();
    if (t == 0 && mi) {
        atomicAdd(&sums[b * 2 + 0], ws[0] + ws[1] + ws[2] + ws[3]);
        atomicAdd(&sums[b * 2 + 1], ws2[0] + ws2[1] + ws2[2] + ws2[3]);
    }
}

// ---------- softmax per row ----------
__global__ __launch_bounds__(256) void softmax_kernel(const float* __restrict__ tsm,
                                                      const int* __restrict__ msk,
                                                      const int* __restrict__ nv,
                                                      const double* __restrict__ sums,
                                                      float* __restrict__ out,
                                                      int N) {
    const int b = blockIdx.y;
    const int i = blockIdx.x;
    const int t = threadIdx.x;
    const float* row  = tsm + ((size_t)b * N + i) * N;
    float*       orow = out + ((size_t)b * N + i) * N;

    const int mi = msk[b * N + i];
    const int n1 = nv[b];
    if (!mi || n1 == 0) {
        for (int j = t; j < N; j += 256) orow[j] = 0.0f;
        return;
    }

    double ntot = (double)n1 * (double)n1;
    double S  = sums[b * 2 + 0];
    double S2 = sums[b * 2 + 1];
    double mean = S / ntot;
    double var  = (ntot > 1.5) ? (S2 - S * S / ntot) / (ntot - 1.0) : 1.0;
    if (var < 1e-30) var = 1e-30;
    float fmean = (float)mean;
    float inv   = (float)(1.0 / (sqrt(var) * (double)TEMP));

    float l[4];
    int   mj[4];
    int nch = (N + 255) / 256;
    float mx = -INFINITY;
    for (int c = 0; c < nch; c++) {
        int j = t + c * 256;
        mj[c] = msk[b * N + j];
        l[c]  = (fmean - row[j]) * inv;
        if (mj[c]) mx = fmaxf(mx, l[c]);
    }
    __shared__ float red[4];
    #pragma unroll
    for (int off = 32; off > 0; off >>= 1) mx = fmaxf(mx, __shfl_down(mx, off, 64));
    if ((t & 63) == 0) red[t >> 6] = mx;
    __syncthreads();
    mx = fmaxf(fmaxf(red[0], red[1]), fmaxf(red[2], red[3]));
    __syncthreads();

    float e[4];
    float sum = 0.0f;
    for (int c = 0; c < nch; c++) {
        e[c] = mj[c] ? __expf(l[c] - mx) : 0.0f;
        sum += e[c];
    }
    #pragma unroll
    for (int off = 32; off > 0; off >>= 1) sum += __shfl_down(sum, off, 64);
    if ((t & 63) == 0) red[t >> 6] = sum;
    __syncthreads();
    sum = red[0] + red[1] + red[2] + red[3];

    float rs = 1.0f / sum;
    for (int c = 0; c < nch; c++) {
        int j = t + c * 256;
        orow[j] = mj[c] ? e[c] * rs : 0.0f;
    }
}

extern "C" void kernel_launch(void* const* d_in, const int* in_sizes, int n_in,
                              void* d_out, int out_size, void* d_ws, size_t ws_size,
                              hipStream_t stream) {
    const float* X    = (const float*)d_in[0];
    const void*  mask = d_in[1];
    const float* pa   = (const float*)d_in[2];
    const float* pb   = (const float*)d_in[3];

    int BN = in_sizes[1];          // B*N
    int N  = out_size / BN;        // 512
    int B  = BN / N;               // 2

    float* out = (float*)d_out;
    char*  ws  = (char*)d_ws;

    size_t off = 0;
    auto alloc = [&](size_t bytes) { size_t o = off; off = (off + bytes + 255) & ~(size_t)255; return o; };
    float*  Phi   = (float*)(ws + alloc((size_t)B * DIMF * N * sizeof(float)));
    float*  cdim  = (float*)(ws + alloc(DIMF * sizeof(float)));
    float*  parts = (float*)(ws + alloc((size_t)SPLITK * B * N * N * sizeof(float)));
    float*  tsm   = (float*)(ws + alloc((size_t)B * N * N * sizeof(float)));
    double* sums  = (double*)(ws + alloc((size_t)B * 2 * sizeof(double)));
    int*    msk   = (int*)(ws + alloc((size_t)B * N * sizeof(int)));
    int*    nv    = (int*)(ws + alloc((size_t)B * sizeof(int)));
    float*  mxb   = (float*)(ws + alloc((size_t)B * sizeof(float)));

    setup_kernel<<<B, 256, 0, stream>>>(X, mask, B, N, msk, nv, sums, mxb);

    dct_kernel<<<KH, 256, 0, stream>>>(pa, pb, mxb, B, cdim);

    dim3 gf(N, B);
    feat_kernel<<<gf, 384, 0, stream>>>(X, pa, pb, mxb, B, N, Phi);

    int nt = N / TSG;
    dim3 gg(nt * nt, SPLITK, B);
    gemm_kernel<<<gg, 256, 0, stream>>>(Phi, cdim, nv, parts, B, N);

    dim3 gr(N, B);
    reduce_stats_kernel<<<gr, 256, 0, stream>>>(parts, msk, tsm, sums, B, N);

    dim3 g2(N, B);
    softmax_kernel<<<g2, 256, 0, stream>>>(tsm, msk, nv, sums, out, N);
}

// Round 8
// 68.577 us; speedup vs baseline: 1.1211x; 1.1211x over previous
//
#include <hip/hip_runtime.h>
#include <math.h>

#define TEMP   13.544f
#define PLAT   18.420680743952367      // -ln(1e-8)
#define KH     192                     // harmonics k = 0..191
#define DIMF   (2*KH)                  // 384 dims: [0..191]=cos_k, [192..383]=sin_k
#define MDCT   512
#define TSG    64                      // gemm tile
#define BKG    16
#define SPLITK 8
#define NMX    16                      // absmax-reduction blocks

// ---------- setup: blocks [0,NMX): absmax partials; blocks [NMX,NMX+B): mask+nv+zero sums ----------
__global__ __launch_bounds__(256) void setup_kernel(const float* __restrict__ X,
                                                    const void* __restrict__ mask_raw,
                                                    int B, int N,
                                                    int* __restrict__ msk,
                                                    int* __restrict__ nv,
                                                    double* __restrict__ sums,
                                                    unsigned int* __restrict__ mxu) {
    int blk = blockIdx.x, t = threadIdx.x;
    if (blk < NMX) {
        const float4* X4 = (const float4*)X;
        int n4 = B * N * 4;
        float m = 0.0f;
        for (int i = blk * 256 + t; i < n4; i += NMX * 256) {
            float4 v = X4[i];
            m = fmaxf(m, fmaxf(fmaxf(fabsf(v.x), fabsf(v.y)), fmaxf(fabsf(v.z), fabsf(v.w))));
        }
        #pragma unroll
        for (int off = 32; off > 0; off >>= 1) m = fmaxf(m, __shfl_down(m, off, 64));
        __shared__ float fmx[4];
        int lane = t & 63, wid = t >> 6;
        if (lane == 0) fmx[wid] = m;
        __syncthreads();
        if (t == 0) {
            float mm = fmaxf(fmaxf(fmx[0], fmx[1]), fmaxf(fmx[2], fmx[3]));
            atomicMax(mxu, __float_as_uint(mm));   // positives: uint order == float order
        }
        return;
    }
    int b = blk - NMX;
    __shared__ int flags[2];
    __shared__ int cnt[4];
    if (t < 2) flags[t] = 0;
    __syncthreads();
    const unsigned int* mi = (const unsigned int*)mask_raw;
    int total = B * N;
    int scan = total < 256 ? total : 256;
    if (t < scan) {
        unsigned int v = mi[t];
        if (v == 0x3F800000u) atomicOr(&flags[0], 1);
        else if (v > 1u)      atomicOr(&flags[1], 1);
    }
    __syncthreads();
    int layout = flags[0] ? 2 : (flags[1] ? 1 : 0);  // 0=i32, 1=u8, 2=f32

    int c = 0;
    for (int j = t; j < N; j += 256) {
        int v;
        if (layout == 0)      v = (((const int*)mask_raw)[b * N + j] != 0);
        else if (layout == 1) v = (((const unsigned char*)mask_raw)[b * N + j] != 0);
        else                  v = (((const float*)mask_raw)[b * N + j] != 0.0f);
        msk[b * N + j] = v;
        c += v;
    }
    #pragma unroll
    for (int off = 32; off > 0; off >>= 1) c += __shfl_down(c, off, 64);
    int lane = t & 63, wid = t >> 6;
    if (lane == 0) cnt[wid] = c;
    __syncthreads();
    if (t == 0) {
        nv[b] = cnt[0] + cnt[1] + cnt[2] + cnt[3];
        sums[b * 2 + 0] = 0.0;
        sums[b * 2 + 1] = 0.0;
    }
}

__device__ __forceinline__ double compute_L(const unsigned int* mxu, double a, double bb) {
    double mx = (double)__uint_as_float(mxu[0]);
    double dsat = sqrt(fmax(42.0 + bb, 1e-6) / a);   // g support: |g|<1e-10 beyond
    double L = fmax(mx + 0.5 * dsat + 0.6, dsat + 0.5);
    return L;
}

__device__ __forceinline__ double g_of(double d, double a, double bb) {
    double w = a * (d * d) - bb;
    double sig = 1.0 / (1.0 + exp(w));               // w>700 -> exp=inf -> sig=0, g=0 exactly
    return -log(sig + 1e-8) - PLAT;
}

// ---------- dct+feat merged: blocks [0,KH): coefficient c_k; blocks [KH,..): features ----------
__global__ __launch_bounds__(256) void dctfeat_kernel(const float* __restrict__ X,
                                                      const float* __restrict__ pa,
                                                      const float* __restrict__ pb,
                                                      const unsigned int* __restrict__ mxu,
                                                      int B, int N,
                                                      float* __restrict__ cdim,
                                                      float* __restrict__ Phi) {
    const int blk = blockIdx.x, t = threadIdx.x;
    double a = (double)pa[0]; if (a < 1e-30) a = 1e-30;
    double bb = (double)pb[0];
    double L = compute_L(mxu, a, bb);

    if (blk < KH) {
        // midpoint DCT: c_k = (k==0?1:2)/M * sum_m g(d_m) cos(om*d_m)
        int k = blk;
        double om = (double)k * M_PI / L;
        double h = L / (double)MDCT;
        double acc = 0.0;
        for (int m = t; m < MDCT; m += 256) {
            double d = ((double)m + 0.5) * h;
            acc += g_of(d, a, bb) * cos(om * d);
        }
        #pragma unroll
        for (int off = 32; off > 0; off >>= 1) acc += __shfl_down(acc, off, 64);
        __shared__ double ws[4];
        int lane = t & 63, wid = t >> 6;
        if (lane == 0) ws[wid] = acc;
        __syncthreads();
        if (t == 0) {
            double c = (ws[0] + ws[1] + ws[2] + ws[3]) * ((k == 0 ? 1.0 : 2.0) / (double)MDCT);
            cdim[k]      = (float)c;
            cdim[KH + k] = (float)c;
        }
        return;
    }

    // feature block: one (row, b); thread k<KH computes C_k, S_k over 16 elements
    int idx = blk - KH;
    int row = idx % N, b = idx / N;
    __shared__ float xs[16];
    if (t < 16) xs[t] = X[((size_t)b * N + row) * 16 + t];
    __syncthreads();
    if (t >= KH) return;
    double om = (double)t * M_PI / L;
    const double inv2pi = 0.15915494309189535;
    const double twopi  = 6.283185307179586;
    float cs = 0.0f, sn = 0.0f;
    #pragma unroll
    for (int e = 0; e < 16; e++) {
        double th = om * (double)xs[e];
        double n = rint(th * inv2pi);
        float tr = (float)(th - twopi * n);
        float s, c;
        __sincosf(tr, &s, &c);
        cs += c; sn += s;
    }
    size_t base = (size_t)b * DIMF * N;
    Phi[base + (size_t)t * N + row]        = cs;
    Phi[base + (size_t)(KH + t) * N + row] = sn;
}

// ---------- gemm: 64x64 tile, 64 threads, 8x8/thread; A scaled by c_k at staging ----------
__global__ __launch_bounds__(64) void gemm_kernel(const float* __restrict__ Phi,
                                                  const float* __restrict__ cdim,
                                                  const int* __restrict__ nv,
                                                  float* __restrict__ parts,
                                                  int B, int N) {
    const int b = blockIdx.z, sk = blockIdx.y, tile = blockIdx.x;
    const int nt = N / TSG;
    const int ti0 = (tile / nt) * TSG, tj0 = (tile % nt) * TSG;
    const int nvb = nv[b];
    if (ti0 >= nvb || tj0 >= nvb) return;   // dead tile: stale parts masked downstream

    __shared__ float As[BKG][TSG];
    __shared__ float Bs[BKG][TSG];
    const int t = threadIdx.x, tr = t >> 3, tc = t & 7;
    float acc[8][8];
    #pragma unroll
    for (int i = 0; i < 8; i++)
        #pragma unroll
        for (int j = 0; j < 8; j++) acc[i][j] = 0.0f;

    const float* Pb = Phi + (size_t)b * DIMF * N;
    const int chunk = DIMF / SPLITK;        // 48
    const int kbase = sk * chunk;

    for (int ch = 0; ch < chunk; ch += BKG) {
        int kb = kbase + ch;
        __syncthreads();
        #pragma unroll
        for (int w = 0; w < 4; w++) {
            int f   = t + 64 * w;           // float4 index 0..255
            int row = f >> 4;               // k-row 0..15
            int c4  = (f & 15) << 2;        // col 0..60
            float ck = cdim[kb + row];
            float4 av = *(const float4*)&Pb[(size_t)(kb + row) * N + ti0 + c4];
            float4 bv = *(const float4*)&Pb[(size_t)(kb + row) * N + tj0 + c4];
            *(float4*)&As[row][c4] = make_float4(av.x * ck, av.y * ck, av.z * ck, av.w * ck);
            *(float4*)&Bs[row][c4] = bv;
        }
        __syncthreads();
        #pragma unroll
        for (int kk = 0; kk < BKG; kk++) {
            float4 a0 = *(const float4*)&As[kk][tr * 8];
            float4 a1 = *(const float4*)&As[kk][tr * 8 + 4];
            float4 b0 = *(const float4*)&Bs[kk][tc * 8];
            float4 b1 = *(const float4*)&Bs[kk][tc * 8 + 4];
            float av_[8] = {a0.x, a0.y, a0.z, a0.w, a1.x, a1.y, a1.z, a1.w};
            float bv_[8] = {b0.x, b0.y, b0.z, b0.w, b1.x, b1.y, b1.z, b1.w};
            #pragma unroll
            for (int i = 0; i < 8; i++)
                #pragma unroll
                for (int j = 0; j < 8; j++)
                    acc[i][j] = fmaf(av_[i], bv_[j], acc[i][j]);
        }
    }
    float* dst = parts + ((size_t)(sk * B + b) * N) * N;
    #pragma unroll
    for (int i = 0; i < 8; i++) {
        size_t r = (size_t)(ti0 + tr * 8 + i) * N + tj0 + tc * 8;
        *(float4*)&dst[r]     = make_float4(acc[i][0], acc[i][1], acc[i][2], acc[i][3]);
        *(float4*)&dst[r + 4] = make_float4(acc[i][4], acc[i][5], acc[i][6], acc[i][7]);
    }
}

// ---------- reduce splitK parts -> tsm, fused masked f64 stats ----------
__global__ __launch_bounds__(256) void reduce_stats_kernel(const float* __restrict__ parts,
                                                           const int* __restrict__ msk,
                                                           float* __restrict__ tsm,
                                                           double* __restrict__ sums,
                                                           int B, int N) {
    const int i = blockIdx.x, b = blockIdx.y, t = threadIdx.x;
    float* orow = tsm + ((size_t)b * N + i) * N;
    const int mi = msk[b * N + i];
    double s = 0.0, s2 = 0.0;
    for (int c = 0; c < N / 256; c++) {
        int j = t + c * 256;
        float v = 0.0f;
        #pragma unroll
        for (int sk = 0; sk < SPLITK; sk++)
            v += parts[(((size_t)sk * B + b) * N + i) * N + j];
        float val = (float)PLAT + v * (1.0f / 256.0f);
        orow[j] = val;
        if (mi && msk[b * N + j]) { double x = (double)val; s += x; s2 += x * x; }
    }
    #pragma unroll
    for (int off = 32; off > 0; off >>= 1) {
        s  += __shfl_down(s,  off, 64);
        s2 += __shfl_down(s2, off, 64);
    }
    __shared__ double ws[4], ws2[4];
    int lane = t & 63, wid = t >> 6;
    if (lane == 0) { ws[wid] = s; ws2[wid] = s2; }
    __syncthreads();
    if (t == 0 && mi) {
        atomicAdd(&sums[b * 2 + 0], ws[0] + ws[1] + ws[2] + ws[3]);
        atomicAdd(&sums[b * 2 + 1], ws2[0] + ws2[1] + ws2[2] + ws2[3]);
    }
}

// ---------- softmax per row ----------
__global__ __launch_bounds__(256) void softmax_kernel(const float* __restrict__ tsm,
                                                      const int* __restrict__ msk,
                                                      const int* __restrict__ nv,
                                                      const double* __restrict__ sums,
                                                      float* __restrict__ out,
                                                      int N) {
    const int b = blockIdx.y;
    const int i = blockIdx.x;
    const int t = threadIdx.x;
    const float* row  = tsm + ((size_t)b * N + i) * N;
    float*       orow = out + ((size_t)b * N + i) * N;

    const int mi = msk[b * N + i];
    const int n1 = nv[b];
    if (!mi || n1 == 0) {
        for (int j = t; j < N; j += 256) orow[j] = 0.0f;
        return;
    }

    double ntot = (double)n1 * (double)n1;
    double S  = sums[b * 2 + 0];
    double S2 = sums[b * 2 + 1];
    double mean = S / ntot;
    double var  = (ntot > 1.5) ? (S2 - S * S / ntot) / (ntot - 1.0) : 1.0;
    if (var < 1e-30) var = 1e-30;
    float fmean = (float)mean;
    float inv   = (float)(1.0 / (sqrt(var) * (double)TEMP));

    float l[4];
    int   mj[4];
    int nch = (N + 255) / 256;
    float mx = -INFINITY;
    for (int c = 0; c < nch; c++) {
        int j = t + c * 256;
        mj[c] = msk[b * N + j];
        l[c]  = (fmean - row[j]) * inv;
        if (mj[c]) mx = fmaxf(mx, l[c]);
    }
    __shared__ float red[4];
    #pragma unroll
    for (int off = 32; off > 0; off >>= 1) mx = fmaxf(mx, __shfl_down(mx, off, 64));
    if ((t & 63) == 0) red[t >> 6] = mx;
    __syncthreads();
    mx = fmaxf(fmaxf(red[0], red[1]), fmaxf(red[2], red[3]));
    __syncthreads();

    float e[4];
    float sum = 0.0f;
    for (int c = 0; c < nch; c++) {
        e[c] = mj[c] ? __expf(l[c] - mx) : 0.0f;
        sum += e[c];
    }
    #pragma unroll
    for (int off = 32; off > 0; off >>= 1) sum += __shfl_down(sum, off, 64);
    if ((t & 63) == 0) red[t >> 6] = sum;
    __syncthreads();
    sum = red[0] + red[1] + red[2] + red[3];

    float rs = 1.0f / sum;
    for (int c = 0; c < nch; c++) {
        int j = t + c * 256;
        orow[j] = mj[c] ? e[c] * rs : 0.0f;
    }
}

extern "C" void kernel_launch(void* const* d_in, const int* in_sizes, int n_in,
                              void* d_out, int out_size, void* d_ws, size_t ws_size,
                              hipStream_t stream) {
    const float* X    = (const float*)d_in[0];
    const void*  mask = d_in[1];
    const float* pa   = (const float*)d_in[2];
    const float* pb   = (const float*)d_in[3];

    int BN = in_sizes[1];          // B*N
    int N  = out_size / BN;        // 512
    int B  = BN / N;               // 2

    float* out = (float*)d_out;
    char*  ws  = (char*)d_ws;

    size_t off = 0;
    auto alloc = [&](size_t bytes) { size_t o = off; off = (off + bytes + 255) & ~(size_t)255; return o; };
    float*        Phi   = (float*)(ws + alloc((size_t)B * DIMF * N * sizeof(float)));
    float*        cdim  = (float*)(ws + alloc(DIMF * sizeof(float)));
    float*        parts = (float*)(ws + alloc((size_t)SPLITK * B * N * N * sizeof(float)));
    float*        tsm   = (float*)(ws + alloc((size_t)B * N * N * sizeof(float)));
    double*       sums  = (double*)(ws + alloc((size_t)B * 2 * sizeof(double)));
    int*          msk   = (int*)(ws + alloc((size_t)B * N * sizeof(int)));
    int*          nv    = (int*)(ws + alloc((size_t)B * sizeof(int)));
    unsigned int* mxu   = (unsigned int*)(ws + alloc(sizeof(unsigned int)));

    hipMemsetAsync(mxu, 0, sizeof(unsigned int), stream);

    setup_kernel<<<NMX + B, 256, 0, stream>>>(X, mask, B, N, msk, nv, sums, mxu);

    dctfeat_kernel<<<KH + N * B, 256, 0, stream>>>(X, pa, pb, mxu, B, N, cdim, Phi);

    int nt = N / TSG;
    dim3 gg(nt * nt, SPLITK, B);
    gemm_kernel<<<gg, 64, 0, stream>>>(Phi, cdim, nv, parts, B, N);

    dim3 gr(N, B);
    reduce_stats_kernel<<<gr, 256, 0, stream>>>(parts, msk, tsm, sums, B, N);

    dim3 g2(N, B);
    softmax_kernel<<<g2, 256, 0, stream>>>(tsm, msk, nv, sums, out, N);
}

// Round 9
// 66.893 us; speedup vs baseline: 1.1493x; 1.0252x over previous
//
#include <hip/hip_runtime.h>
#include <math.h>

#define TEMP   13.544f
#define PLAT   18.420680743952367      // -ln(1e-8)
#define KH     192                     // harmonics k = 0..191
#define DIMF   (2*KH)                  // 384 dims: [0..191]=cos_k, [192..383]=sin_k
#define MDCT   512
#define TSG    64                      // gemm tile
#define BKG    16
#define SPLITK 8
#define NMX    16                      // absmax-reduction blocks

// ---------- setup: blocks [0,NMX): absmax partials -> mxp[blk]; blocks [NMX,NMX+B): mask+nv+zero sums ----------
__global__ __launch_bounds__(256) void setup_kernel(const float* __restrict__ X,
                                                    const void* __restrict__ mask_raw,
                                                    int B, int N,
                                                    int* __restrict__ msk,
                                                    int* __restrict__ nv,
                                                    double* __restrict__ sums,
                                                    float* __restrict__ mxp) {
    int blk = blockIdx.x, t = threadIdx.x;
    if (blk < NMX) {
        const float4* X4 = (const float4*)X;
        int n4 = B * N * 4;
        float m = 0.0f;
        for (int i = blk * 256 + t; i < n4; i += NMX * 256) {
            float4 v = X4[i];
            m = fmaxf(m, fmaxf(fmaxf(fabsf(v.x), fabsf(v.y)), fmaxf(fabsf(v.z), fabsf(v.w))));
        }
        #pragma unroll
        for (int off = 32; off > 0; off >>= 1) m = fmaxf(m, __shfl_down(m, off, 64));
        __shared__ float fmx[4];
        int lane = t & 63, wid = t >> 6;
        if (lane == 0) fmx[wid] = m;
        __syncthreads();
        if (t == 0) mxp[blk] = fmaxf(fmaxf(fmx[0], fmx[1]), fmaxf(fmx[2], fmx[3]));
        return;
    }
    int b = blk - NMX;
    __shared__ int flags[2];
    __shared__ int cnt[4];
    if (t < 2) flags[t] = 0;
    __syncthreads();
    const unsigned int* mi = (const unsigned int*)mask_raw;
    int total = B * N;
    int scan = total < 256 ? total : 256;
    if (t < scan) {
        unsigned int v = mi[t];
        if (v == 0x3F800000u) atomicOr(&flags[0], 1);
        else if (v > 1u)      atomicOr(&flags[1], 1);
    }
    __syncthreads();
    int layout = flags[0] ? 2 : (flags[1] ? 1 : 0);  // 0=i32, 1=u8, 2=f32

    int c = 0;
    for (int j = t; j < N; j += 256) {
        int v;
        if (layout == 0)      v = (((const int*)mask_raw)[b * N + j] != 0);
        else if (layout == 1) v = (((const unsigned char*)mask_raw)[b * N + j] != 0);
        else                  v = (((const float*)mask_raw)[b * N + j] != 0.0f);
        msk[b * N + j] = v;
        c += v;
    }
    #pragma unroll
    for (int off = 32; off > 0; off >>= 1) c += __shfl_down(c, off, 64);
    int lane = t & 63, wid = t >> 6;
    if (lane == 0) cnt[wid] = c;
    __syncthreads();
    if (t == 0) {
        nv[b] = cnt[0] + cnt[1] + cnt[2] + cnt[3];
        sums[b * 2 + 0] = 0.0;
        sums[b * 2 + 1] = 0.0;
    }
}

__device__ __forceinline__ double compute_L(const float* __restrict__ mxp, double a, double bb) {
    float m = 0.0f;
    #pragma unroll
    for (int i = 0; i < NMX; i++) m = fmaxf(m, mxp[i]);
    double mx = (double)m;
    double dsat = sqrt(fmax(42.0 + bb, 1e-6) / a);   // g support: |g|<1e-10 beyond
    // periodic wrap is safe: for d in (L, 2L), both g(d) and g(2L-d) are 0
    // because 2L - 2*mx >= dsat by construction.
    double L = fmax(mx + 0.5 * dsat + 0.6, dsat + 0.5);
    return L;
}

__device__ __forceinline__ double g_of(double d, double a, double bb) {
    double w = a * (d * d) - bb;
    double sig = 1.0 / (1.0 + exp(w));               // w>700 -> exp=inf -> sig=0, g=0 exactly
    return -log(sig + 1e-8) - PLAT;
}

// ---------- dct+feat merged: blocks [0,KH): coefficient c_k; blocks [KH,..): features ----------
__global__ __launch_bounds__(256) void dctfeat_kernel(const float* __restrict__ X,
                                                      const float* __restrict__ pa,
                                                      const float* __restrict__ pb,
                                                      const float* __restrict__ mxp,
                                                      int B, int N,
                                                      float* __restrict__ cdim,
                                                      float* __restrict__ Phi) {
    const int blk = blockIdx.x, t = threadIdx.x;
    double a = (double)pa[0]; if (a < 1e-30) a = 1e-30;
    double bb = (double)pb[0];
    double L = compute_L(mxp, a, bb);

    if (blk < KH) {
        // midpoint DCT: c_k = (k==0?1:2)/M * sum_m g(d_m) cos(om*d_m)
        int k = blk;
        double om = (double)k * M_PI / L;
        double h = L / (double)MDCT;
        double acc = 0.0;
        for (int m = t; m < MDCT; m += 256) {
            double d = ((double)m + 0.5) * h;
            acc += g_of(d, a, bb) * cos(om * d);
        }
        #pragma unroll
        for (int off = 32; off > 0; off >>= 1) acc += __shfl_down(acc, off, 64);
        __shared__ double ws[4];
        int lane = t & 63, wid = t >> 6;
        if (lane == 0) ws[wid] = acc;
        __syncthreads();
        if (t == 0) {
            double c = (ws[0] + ws[1] + ws[2] + ws[3]) * ((k == 0 ? 1.0 : 2.0) / (double)MDCT);
            cdim[k]      = (float)c;
            cdim[KH + k] = (float)c;
        }
        return;
    }

    // feature block: one (row, b); thread k<KH computes C_k, S_k over 16 elements
    int idx = blk - KH;
    int row = idx % N, b = idx / N;
    __shared__ float xs[16];
    if (t < 16) xs[t] = X[((size_t)b * N + row) * 16 + t];
    __syncthreads();
    if (t >= KH) return;
    double om = (double)t * M_PI / L;
    const double inv2pi = 0.15915494309189535;
    const double twopi  = 6.283185307179586;
    float cs = 0.0f, sn = 0.0f;
    #pragma unroll
    for (int e = 0; e < 16; e++) {
        double th = om * (double)xs[e];
        double n = rint(th * inv2pi);
        float tr = (float)(th - twopi * n);
        float s, c;
        __sincosf(tr, &s, &c);
        cs += c; sn += s;
    }
    size_t base = (size_t)b * DIMF * N;
    Phi[base + (size_t)t * N + row]        = cs;
    Phi[base + (size_t)(KH + t) * N + row] = sn;
}

// ---------- gemm: 64x64 tile, 64 threads, 8x8/thread; A scaled by c_k at staging ----------
__global__ __launch_bounds__(64) void gemm_kernel(const float* __restrict__ Phi,
                                                  const float* __restrict__ cdim,
                                                  const int* __restrict__ nv,
                                                  float* __restrict__ parts,
                                                  int B, int N) {
    const int b = blockIdx.z, sk = blockIdx.y, tile = blockIdx.x;
    const int nt = N / TSG;
    const int ti0 = (tile / nt) * TSG, tj0 = (tile % nt) * TSG;
    const int nvb = nv[b];
    if (ti0 >= nvb || tj0 >= nvb) return;   // dead tile: stale parts masked downstream

    __shared__ float As[BKG][TSG];
    __shared__ float Bs[BKG][TSG];
    const int t = threadIdx.x, tr = t >> 3, tc = t & 7;
    float acc[8][8];
    #pragma unroll
    for (int i = 0; i < 8; i++)
        #pragma unroll
        for (int j = 0; j < 8; j++) acc[i][j] = 0.0f;

    const float* Pb = Phi + (size_t)b * DIMF * N;
    const int chunk = DIMF / SPLITK;        // 48
    const int kbase = sk * chunk;

    for (int ch = 0; ch < chunk; ch += BKG) {
        int kb = kbase + ch;
        __syncthreads();
        #pragma unroll
        for (int w = 0; w < 4; w++) {
            int f   = t + 64 * w;           // float4 index 0..255
            int row = f >> 4;               // k-row 0..15
            int c4  = (f & 15) << 2;        // col 0..60
            float ck = cdim[kb + row];
            float4 av = *(const float4*)&Pb[(size_t)(kb + row) * N + ti0 + c4];
            float4 bv = *(const float4*)&Pb[(size_t)(kb + row) * N + tj0 + c4];
            *(float4*)&As[row][c4] = make_float4(av.x * ck, av.y * ck, av.z * ck, av.w * ck);
            *(float4*)&Bs[row][c4] = bv;
        }
        __syncthreads();
        #pragma unroll
        for (int kk = 0; kk < BKG; kk++) {
            float4 a0 = *(const float4*)&As[kk][tr * 8];
            float4 a1 = *(const float4*)&As[kk][tr * 8 + 4];
            float4 b0 = *(const float4*)&Bs[kk][tc * 8];
            float4 b1 = *(const float4*)&Bs[kk][tc * 8 + 4];
            float av_[8] = {a0.x, a0.y, a0.z, a0.w, a1.x, a1.y, a1.z, a1.w};
            float bv_[8] = {b0.x, b0.y, b0.z, b0.w, b1.x, b1.y, b1.z, b1.w};
            #pragma unroll
            for (int i = 0; i < 8; i++)
                #pragma unroll
                for (int j = 0; j < 8; j++)
                    acc[i][j] = fmaf(av_[i], bv_[j], acc[i][j]);
        }
    }
    float* dst = parts + ((size_t)(sk * B + b) * N) * N;
    #pragma unroll
    for (int i = 0; i < 8; i++) {
        size_t r = (size_t)(ti0 + tr * 8 + i) * N + tj0 + tc * 8;
        *(float4*)&dst[r]     = make_float4(acc[i][0], acc[i][1], acc[i][2], acc[i][3]);
        *(float4*)&dst[r + 4] = make_float4(acc[i][4], acc[i][5], acc[i][6], acc[i][7]);
    }
}

// ---------- reduce splitK parts -> tsm, fused masked f64 stats ----------
__global__ __launch_bounds__(256) void reduce_stats_kernel(const float* __restrict__ parts,
                                                           const int* __restrict__ msk,
                                                           float* __restrict__ tsm,
                                                           double* __restrict__ sums,
                                                           int B, int N) {
    const int i = blockIdx.x, b = blockIdx.y, t = threadIdx.x;
    float* orow = tsm + ((size_t)b * N + i) * N;
    const int mi = msk[b * N + i];
    double s = 0.0, s2 = 0.0;
    for (int c = 0; c < N / 256; c++) {
        int j = t + c * 256;
        float v = 0.0f;
        #pragma unroll
        for (int sk = 0; sk < SPLITK; sk++)
            v += parts[(((size_t)sk * B + b) * N + i) * N + j];
        float val = (float)PLAT + v * (1.0f / 256.0f);
        orow[j] = val;
        if (mi && msk[b * N + j]) { double x = (double)val; s += x; s2 += x * x; }
    }
    #pragma unroll
    for (int off = 32; off > 0; off >>= 1) {
        s  += __shfl_down(s,  off, 64);
        s2 += __shfl_down(s2, off, 64);
    }
    __shared__ double ws[4], ws2[4];
    int lane = t & 63, wid = t >> 6;
    if (lane == 0) { ws[wid] = s; ws2[wid] = s2; }
    __syncthreads();
    if (t == 0 && mi) {
        atomicAdd(&sums[b * 2 + 0], ws[0] + ws[1] + ws[2] + ws[3]);
        atomicAdd(&sums[b * 2 + 1], ws2[0] + ws2[1] + ws2[2] + ws2[3]);
    }
}

// ---------- softmax per row ----------
__global__ __launch_bounds__(256) void softmax_kernel(const float* __restrict__ tsm,
                                                      const int* __restrict__ msk,
                                                      const int* __restrict__ nv,
                                                      const double* __restrict__ sums,
                                                      float* __restrict__ out,
                                                      int N) {
    const int b = blockIdx.y;
    const int i = blockIdx.x;
    const int t = threadIdx.x;
    const float* row  = tsm + ((size_t)b * N + i) * N;
    float*       orow = out + ((size_t)b * N + i) * N;

    const int mi = msk[b * N + i];
    const int n1 = nv[b];
    if (!mi || n1 == 0) {
        for (int j = t; j < N; j += 256) orow[j] = 0.0f;
        return;
    }

    double ntot = (double)n1 * (double)n1;
    double S  = sums[b * 2 + 0];
    double S2 = sums[b * 2 + 1];
    double mean = S / ntot;
    double var  = (ntot > 1.5) ? (S2 - S * S / ntot) / (ntot - 1.0) : 1.0;
    if (var < 1e-30) var = 1e-30;
    float fmean = (float)mean;
    float inv   = (float)(1.0 / (sqrt(var) * (double)TEMP));

    float l[4];
    int   mj[4];
    int nch = (N + 255) / 256;
    float mx = -INFINITY;
    for (int c = 0; c < nch; c++) {
        int j = t + c * 256;
        mj[c] = msk[b * N + j];
        l[c]  = (fmean - row[j]) * inv;
        if (mj[c]) mx = fmaxf(mx, l[c]);
    }
    __shared__ float red[4];
    #pragma unroll
    for (int off = 32; off > 0; off >>= 1) mx = fmaxf(mx, __shfl_down(mx, off, 64));
    if ((t & 63) == 0) red[t >> 6] = mx;
    __syncthreads();
    mx = fmaxf(fmaxf(red[0], red[1]), fmaxf(red[2], red[3]));
    __syncthreads();

    float e[4];
    float sum = 0.0f;
    for (int c = 0; c < nch; c++) {
        e[c] = mj[c] ? __expf(l[c] - mx) : 0.0f;
        sum += e[c];
    }
    #pragma unroll
    for (int off = 32; off > 0; off >>= 1) sum += __shfl_down(sum, off, 64);
    if ((t & 63) == 0) red[t >> 6] = sum;
    __syncthreads();
    sum = red[0] + red[1] + red[2] + red[3];

    float rs = 1.0f / sum;
    for (int c = 0; c < nch; c++) {
        int j = t + c * 256;
        orow[j] = mj[c] ? e[c] * rs : 0.0f;
    }
}

extern "C" void kernel_launch(void* const* d_in, const int* in_sizes, int n_in,
                              void* d_out, int out_size, void* d_ws, size_t ws_size,
                              hipStream_t stream) {
    const float* X    = (const float*)d_in[0];
    const void*  mask = d_in[1];
    const float* pa   = (const float*)d_in[2];
    const float* pb   = (const float*)d_in[3];

    int BN = in_sizes[1];          // B*N
    int N  = out_size / BN;        // 512
    int B  = BN / N;               // 2

    float* out = (float*)d_out;
    char*  ws  = (char*)d_ws;

    size_t off = 0;
    auto alloc = [&](size_t bytes) { size_t o = off; off = (off + bytes + 255) & ~(size_t)255; return o; };
    float*  Phi   = (float*)(ws + alloc((size_t)B * DIMF * N * sizeof(float)));
    float*  cdim  = (float*)(ws + alloc(DIMF * sizeof(float)));
    float*  parts = (float*)(ws + alloc((size_t)SPLITK * B * N * N * sizeof(float)));
    float*  tsm   = (float*)(ws + alloc((size_t)B * N * N * sizeof(float)));
    double* sums  = (double*)(ws + alloc((size_t)B * 2 * sizeof(double)));
    int*    msk   = (int*)(ws + alloc((size_t)B * N * sizeof(int)));
    int*    nv    = (int*)(ws + alloc((size_t)B * sizeof(int)));
    float*  mxp   = (float*)(ws + alloc((size_t)NMX * sizeof(float)));

    setup_kernel<<<NMX + B, 256, 0, stream>>>(X, mask, B, N, msk, nv, sums, mxp);

    dctfeat_kernel<<<KH + N * B, 256, 0, stream>>>(X, pa, pb, mxp, B, N, cdim, Phi);

    int nt = N / TSG;
    dim3 gg(nt * nt, SPLITK, B);
    gemm_kernel<<<gg, 64, 0, stream>>>(Phi, cdim, nv, parts, B, N);

    dim3 gr(N, B);
    reduce_stats_kernel<<<gr, 256, 0, stream>>>(parts, msk, tsm, sums, B, N);

    dim3 g2(N, B);
    softmax_kernel<<<g2, 256, 0, stream>>>(tsm, msk, nv, sums, out, N);
}

// Round 10
// 65.241 us; speedup vs baseline: 1.1784x; 1.0253x over previous
//
#include <hip/hip_runtime.h>
#include <math.h>

#define TEMP   13.544f
#define PLAT   18.420680743952367      // -ln(1e-8)
#define KH     192                     // harmonics k = 0..191
#define DIMF   (2*KH)                  // 384 dims: [0..191]=cos_k, [192..383]=sin_k
#define MDCT   512
#define TSG    64                      // gemm tile
#define BKG    16
#define SPLITK 4
#define NMX    16                      // absmax-reduction blocks
#define KCH    3                       // feat k-chunks (KH/64)

// ---------- setup: blocks [0,NMX): absmax partials -> mxp; blocks [NMX,NMX+B): mask+nv+zero sums ----------
__global__ __launch_bounds__(256) void setup_kernel(const float* __restrict__ X,
                                                    const void* __restrict__ mask_raw,
                                                    int B, int N,
                                                    int* __restrict__ msk,
                                                    int* __restrict__ nv,
                                                    double* __restrict__ sums,
                                                    float* __restrict__ mxp) {
    int blk = blockIdx.x, t = threadIdx.x;
    if (blk < NMX) {
        const float4* X4 = (const float4*)X;
        int n4 = B * N * 4;
        float m = 0.0f;
        for (int i = blk * 256 + t; i < n4; i += NMX * 256) {
            float4 v = X4[i];
            m = fmaxf(m, fmaxf(fmaxf(fabsf(v.x), fabsf(v.y)), fmaxf(fabsf(v.z), fabsf(v.w))));
        }
        #pragma unroll
        for (int off = 32; off > 0; off >>= 1) m = fmaxf(m, __shfl_down(m, off, 64));
        __shared__ float fmx[4];
        int lane = t & 63, wid = t >> 6;
        if (lane == 0) fmx[wid] = m;
        __syncthreads();
        if (t == 0) mxp[blk] = fmaxf(fmaxf(fmx[0], fmx[1]), fmaxf(fmx[2], fmx[3]));
        return;
    }
    int b = blk - NMX;
    __shared__ int flags[2];
    __shared__ int cnt[4];
    if (t < 2) flags[t] = 0;
    __syncthreads();
    const unsigned int* mi = (const unsigned int*)mask_raw;
    int total = B * N;
    int scan = total < 256 ? total : 256;
    if (t < scan) {
        unsigned int v = mi[t];
        if (v == 0x3F800000u) atomicOr(&flags[0], 1);
        else if (v > 1u)      atomicOr(&flags[1], 1);
    }
    __syncthreads();
    int layout = flags[0] ? 2 : (flags[1] ? 1 : 0);  // 0=i32, 1=u8, 2=f32

    int c = 0;
    for (int j = t; j < N; j += 256) {
        int v;
        if (layout == 0)      v = (((const int*)mask_raw)[b * N + j] != 0);
        else if (layout == 1) v = (((const unsigned char*)mask_raw)[b * N + j] != 0);
        else                  v = (((const float*)mask_raw)[b * N + j] != 0.0f);
        msk[b * N + j] = v;
        c += v;
    }
    #pragma unroll
    for (int off = 32; off > 0; off >>= 1) c += __shfl_down(c, off, 64);
    int lane = t & 63, wid = t >> 6;
    if (lane == 0) cnt[wid] = c;
    __syncthreads();
    if (t == 0) {
        nv[b] = cnt[0] + cnt[1] + cnt[2] + cnt[3];
        sums[b * 2 + 0] = 0.0;
        sums[b * 2 + 1] = 0.0;
    }
}

__device__ __forceinline__ double compute_L(const float* __restrict__ mxp, double a, double bb) {
    float m = 0.0f;
    #pragma unroll
    for (int i = 0; i < NMX; i++) m = fmaxf(m, mxp[i]);
    double mx = (double)m;
    double dsat = sqrt(fmax(42.0 + bb, 1e-6) / a);   // g support: |g|<1e-10 beyond
    double L = fmax(mx + 0.5 * dsat + 0.6, dsat + 0.5);
    return L;
}

__device__ __forceinline__ double g_of(double d, double a, double bb) {
    double w = a * (d * d) - bb;
    double sig = 1.0 / (1.0 + exp(w));               // w>700 -> exp=inf -> sig=0, g=0 exactly
    return -log(sig + 1e-8) - PLAT;
}

// ---------- dct+feat: blocks [0,KH): coefficient c_k; blocks [KH,..): 16 rows x 64 k, coalesced ----------
__global__ __launch_bounds__(256) void dctfeat_kernel(const float* __restrict__ X,
                                                      const float* __restrict__ pa,
                                                      const float* __restrict__ pb,
                                                      const float* __restrict__ mxp,
                                                      int B, int N,
                                                      float* __restrict__ cdim,
                                                      float* __restrict__ Phi) {
    const int blk = blockIdx.x, t = threadIdx.x;
    double a = (double)pa[0]; if (a < 1e-30) a = 1e-30;
    double bb = (double)pb[0];
    double L = compute_L(mxp, a, bb);

    if (blk < KH) {
        int k = blk;
        double om = (double)k * M_PI / L;
        double h = L / (double)MDCT;
        double acc = 0.0;
        for (int m = t; m < MDCT; m += 256) {
            double d = ((double)m + 0.5) * h;
            acc += g_of(d, a, bb) * cos(om * d);
        }
        #pragma unroll
        for (int off = 32; off > 0; off >>= 1) acc += __shfl_down(acc, off, 64);
        __shared__ double ws[4];
        int lane = t & 63, wid = t >> 6;
        if (lane == 0) ws[wid] = acc;
        __syncthreads();
        if (t == 0) {
            double c = (ws[0] + ws[1] + ws[2] + ws[3]) * ((k == 0 ? 1.0 : 2.0) / (double)MDCT);
            cdim[k]      = (float)c;
            cdim[KH + k] = (float)c;
        }
        return;
    }

    // feature block: 16 global rows x 64 harmonics. lane%16 = row, lane/16 = k (16 k per pass, 4 passes)
    int idx = blk - KH;                 // 0 .. (B*N/16)*KCH - 1
    int rg = idx / KCH, kc = idx % KCH;
    int g0 = rg * 16;                   // first flattened row (b*N+row)
    __shared__ float xs[16 * 17];       // padded: row r at xs[r*17 + e]
    {
        int r = t >> 4, e = t & 15;
        xs[r * 17 + e] = X[(size_t)g0 * 16 + t];
    }
    __syncthreads();

    const int rl = t & 15;              // local row
    const int g  = g0 + rl;             // flattened global row
    const int b  = g / N, row = g % N;
    const double inv2pi = 0.15915494309189535;
    const double twopi  = 6.283185307179586;
    size_t base = (size_t)b * DIMF * N;

    #pragma unroll
    for (int pass = 0; pass < 4; pass++) {
        int k = kc * 64 + pass * 16 + (t >> 4);
        double om = (double)k * M_PI / L;
        float cs = 0.0f, sn = 0.0f;
        #pragma unroll
        for (int e = 0; e < 16; e++) {
            double th = om * (double)xs[rl * 17 + e];
            double n = rint(th * inv2pi);
            float tr = (float)(th - twopi * n);
            float s, c;
            __sincosf(tr, &s, &c);
            cs += c; sn += s;
        }
        Phi[base + (size_t)k * N + row]        = cs;   // 16 consecutive rows per 16-lane group
        Phi[base + (size_t)(KH + k) * N + row] = sn;
    }
}

// ---------- gemm: 64x64 tile, 256 thr, 4x4 frag, SPLITK=4, atomicAdd into zeroed tsm ----------
__global__ __launch_bounds__(256) void gemm_kernel(const float* __restrict__ Phi,
                                                   const float* __restrict__ cdim,
                                                   const int* __restrict__ nv,
                                                   float* __restrict__ tsm,
                                                   int B, int N) {
    const int b = blockIdx.z, sk = blockIdx.y, tile = blockIdx.x;
    const int nt = N / TSG;
    const int ti0 = (tile / nt) * TSG, tj0 = (tile % nt) * TSG;
    const int nvb = nv[b];
    if (ti0 >= nvb || tj0 >= nvb) return;   // dead tile: tsm stays 0, masked downstream

    __shared__ float As[BKG][TSG];
    __shared__ float Bs[BKG][TSG];
    const int t = threadIdx.x, tr = t >> 4, tc = t & 15;
    float acc[4][4] = {{0.0f}};

    const float* Pb = Phi + (size_t)b * DIMF * N;
    const int chunk = DIMF / SPLITK;        // 96
    const int kbase = sk * chunk;

    const int srow = t >> 4;                // staging k-row 0..15
    const int sc4  = (t & 15) * 4;          // staging col*4

    for (int ch = 0; ch < chunk; ch += BKG) {
        int kb = kbase + ch;
        __syncthreads();
        {
            float ck = cdim[kb + srow];
            float4 av = *(const float4*)&Pb[(size_t)(kb + srow) * N + ti0 + sc4];
            float4 bv = *(const float4*)&Pb[(size_t)(kb + srow) * N + tj0 + sc4];
            *(float4*)&As[srow][sc4] = make_float4(av.x * ck, av.y * ck, av.z * ck, av.w * ck);
            *(float4*)&Bs[srow][sc4] = bv;
        }
        __syncthreads();
        #pragma unroll
        for (int kk = 0; kk < BKG; kk++) {
            float4 a4 = *(const float4*)&As[kk][tr * 4];
            float4 b4 = *(const float4*)&Bs[kk][tc * 4];
            float av_[4] = {a4.x, a4.y, a4.z, a4.w};
            float bv_[4] = {b4.x, b4.y, b4.z, b4.w};
            #pragma unroll
            for (int i = 0; i < 4; i++)
                #pragma unroll
                for (int j = 0; j < 4; j++)
                    acc[i][j] = fmaf(av_[i], bv_[j], acc[i][j]);
        }
    }
    #pragma unroll
    for (int i = 0; i < 4; i++) {
        size_t r = (size_t)(b * N + ti0 + tr * 4 + i) * N + tj0 + tc * 4;
        #pragma unroll
        for (int j = 0; j < 4; j++)
            atomicAdd(&tsm[r + j], acc[i][j] * (1.0f / 256.0f));
    }
}

// ---------- stats: masked f64 sum/sumsq of (PLAT + tsm_raw) ----------
__global__ __launch_bounds__(256) void stats_kernel(const float* __restrict__ tsm,
                                                    const int* __restrict__ msk,
                                                    double* __restrict__ sums,
                                                    int N) {
    const int b = blockIdx.y;
    const int t = threadIdx.x;
    double s = 0.0, s2 = 0.0;
    for (int i = blockIdx.x; i < N; i += gridDim.x) {
        if (!msk[b * N + i]) continue;
        const float* row = tsm + ((size_t)b * N + i) * N;
        for (int j = t; j < N; j += 256) {
            if (msk[b * N + j]) {
                double x = PLAT + (double)row[j];
                s += x; s2 += x * x;
            }
        }
    }
    #pragma unroll
    for (int off = 32; off > 0; off >>= 1) {
        s  += __shfl_down(s,  off, 64);
        s2 += __shfl_down(s2, off, 64);
    }
    __shared__ double ws[4], ws2[4];
    int lane = t & 63, wid = t >> 6;
    if (lane == 0) { ws[wid] = s; ws2[wid] = s2; }
    __syncthreads();
    if (t == 0) {
        atomicAdd(&sums[b * 2 + 0], ws[0] + ws[1] + ws[2] + ws[3]);
        atomicAdd(&sums[b * 2 + 1], ws2[0] + ws2[1] + ws2[2] + ws2[3]);
    }
}

// ---------- softmax per row (tsm holds raw; val = PLAT + raw) ----------
__global__ __launch_bounds__(256) void softmax_kernel(const float* __restrict__ tsm,
                                                      const int* __restrict__ msk,
                                                      const int* __restrict__ nv,
                                                      const double* __restrict__ sums,
                                                      float* __restrict__ out,
                                                      int N) {
    const int b = blockIdx.y;
    const int i = blockIdx.x;
    const int t = threadIdx.x;
    const float* row  = tsm + ((size_t)b * N + i) * N;
    float*       orow = out + ((size_t)b * N + i) * N;

    const int mi = msk[b * N + i];
    const int n1 = nv[b];
    if (!mi || n1 == 0) {
        for (int j = t; j < N; j += 256) orow[j] = 0.0f;
        return;
    }

    double ntot = (double)n1 * (double)n1;
    double S  = sums[b * 2 + 0];
    double S2 = sums[b * 2 + 1];
    double mean = S / ntot;
    double var  = (ntot > 1.5) ? (S2 - S * S / ntot) / (ntot - 1.0) : 1.0;
    if (var < 1e-30) var = 1e-30;
    float fmean = (float)(mean - PLAT);   // compare against raw + PLAT: (mean - (PLAT+raw)) = (fmean - raw)
    float inv   = (float)(1.0 / (sqrt(var) * (double)TEMP));

    float l[4];
    int   mj[4];
    int nch = (N + 255) / 256;
    float mx = -INFINITY;
    for (int c = 0; c < nch; c++) {
        int j = t + c * 256;
        mj[c] = msk[b * N + j];
        l[c]  = (fmean - row[j]) * inv;
        if (mj[c]) mx = fmaxf(mx, l[c]);
    }
    __shared__ float red[4];
    #pragma unroll
    for (int off = 32; off > 0; off >>= 1) mx = fmaxf(mx, __shfl_down(mx, off, 64));
    if ((t & 63) == 0) red[t >> 6] = mx;
    __syncthreads();
    mx = fmaxf(fmaxf(red[0], red[1]), fmaxf(red[2], red[3]));
    __syncthreads();

    float e[4];
    float sum = 0.0f;
    for (int c = 0; c < nch; c++) {
        e[c] = mj[c] ? __expf(l[c] - mx) : 0.0f;
        sum += e[c];
    }
    #pragma unroll
    for (int off = 32; off > 0; off >>= 1) sum += __shfl_down(sum, off, 64);
    if ((t & 63) == 0) red[t >> 6] = sum;
    __syncthreads();
    sum = red[0] + red[1] + red[2] + red[3];

    float rs = 1.0f / sum;
    for (int c = 0; c < nch; c++) {
        int j = t + c * 256;
        orow[j] = mj[c] ? e[c] * rs : 0.0f;
    }
}

extern "C" void kernel_launch(void* const* d_in, const int* in_sizes, int n_in,
                              void* d_out, int out_size, void* d_ws, size_t ws_size,
                              hipStream_t stream) {
    const float* X    = (const float*)d_in[0];
    const void*  mask = d_in[1];
    const float* pa   = (const float*)d_in[2];
    const float* pb   = (const float*)d_in[3];

    int BN = in_sizes[1];          // B*N
    int N  = out_size / BN;        // 512
    int B  = BN / N;               // 2

    float* out = (float*)d_out;
    char*  ws  = (char*)d_ws;

    size_t off = 0;
    auto alloc = [&](size_t bytes) { size_t o = off; off = (off + bytes + 255) & ~(size_t)255; return o; };
    float*  Phi   = (float*)(ws + alloc((size_t)B * DIMF * N * sizeof(float)));
    float*  cdim  = (float*)(ws + alloc(DIMF * sizeof(float)));
    float*  tsm   = (float*)(ws + alloc((size_t)B * N * N * sizeof(float)));
    double* sums  = (double*)(ws + alloc((size_t)B * 2 * sizeof(double)));
    int*    msk   = (int*)(ws + alloc((size_t)B * N * sizeof(int)));
    int*    nv    = (int*)(ws + alloc((size_t)B * sizeof(int)));
    float*  mxp   = (float*)(ws + alloc((size_t)NMX * sizeof(float)));

    size_t tsmBytes = (size_t)B * N * N * sizeof(float);
    hipMemsetAsync(tsm, 0, tsmBytes, stream);   // atomic accumulation target

    setup_kernel<<<NMX + B, 256, 0, stream>>>(X, mask, B, N, msk, nv, sums, mxp);

    int featBlocks = (B * N / 16) * KCH;
    dctfeat_kernel<<<KH + featBlocks, 256, 0, stream>>>(X, pa, pb, mxp, B, N, cdim, Phi);

    int nt = N / TSG;
    dim3 gg(nt * nt, SPLITK, B);
    gemm_kernel<<<gg, 256, 0, stream>>>(Phi, cdim, nv, tsm, B, N);

    dim3 gs(64, B);
    stats_kernel<<<gs, 256, 0, stream>>>(tsm, msk, sums, N);

    dim3 g2(N, B);
    softmax_kernel<<<g2, 256, 0, stream>>>(tsm, msk, nv, sums, out, N);
}